// Round 5
// baseline (228.760 us; speedup 1.0000x reference)
//
#include <hip/hip_runtime.h>
#include <cstddef>
#include <cstdint>

// Problem constants (B=2, S=2048, D=1024, H=16, hd=64)
constexpr int Bb = 2, Ss = 2048, Dd = 1024, Hh = 16, HD = 64;
constexpr int Mm = Bb * Ss;  // 4096 rows

typedef int v4i __attribute__((ext_vector_type(4)));
typedef __bf16 bf16x8 __attribute__((ext_vector_type(8)));
typedef __bf16 bf16x2 __attribute__((ext_vector_type(2)));
typedef float f32x16 __attribute__((ext_vector_type(16)));

// ln2 folding: q *= 0.125 * 1/ln2 so p = exp2(score) is one v_exp_f32
#define QPOSTMUL 0.18033688f

__device__ __forceinline__ float qscale(float amax) {
    return fmaxf(amax / 127.0f, 1e-8f);
}

// round-to-nearest-even f32 -> bf16 bits
__device__ __forceinline__ unsigned short bf16rtn(float x) {
    __bf16 b = (__bf16)x;
    return __builtin_bit_cast(unsigned short, b);
}

// pack two f32 -> bf16x2 in one u32 (compiler emits v_cvt_pk_bf16_f32)
__device__ __forceinline__ unsigned pack_bf16x2(float a, float b) {
    bf16x2 h;
    h[0] = (__bf16)a;
    h[1] = (__bf16)b;
    return __builtin_bit_cast(unsigned, h);
}

// ---------------- fused amax: hidden (slot0) + 4 weights (slots 1-4) ----------------
__global__ void amax_all(const float4* __restrict__ hidden,
                         const float4* __restrict__ w0, const float4* __restrict__ w1,
                         const float4* __restrict__ w2, const float4* __restrict__ w3,
                         unsigned* __restrict__ slots) {
    const float4* src; int n4, slot, bx, nb;
    if (blockIdx.x < 448) { src = hidden; n4 = Mm * Dd / 4; slot = 0; bx = blockIdx.x; nb = 448; }
    else {
        int w = (blockIdx.x - 448) >> 4; bx = (blockIdx.x - 448) & 15; nb = 16;
        src = w == 0 ? w0 : w == 1 ? w1 : w == 2 ? w2 : w3;
        n4 = Dd * Dd / 4; slot = 1 + w;
    }
    float m = 0.f;
    for (int i = bx * blockDim.x + threadIdx.x; i < n4; i += nb * blockDim.x) {
        float4 v = src[i];
        m = fmaxf(m, fmaxf(fmaxf(fabsf(v.x), fabsf(v.y)), fmaxf(fabsf(v.z), fabsf(v.w))));
    }
    #pragma unroll
    for (int off = 32; off > 0; off >>= 1) m = fmaxf(m, __shfl_down(m, off, 64));
    __shared__ float sm[4];
    int lane = threadIdx.x & 63, wid = threadIdx.x >> 6;
    if (lane == 0) sm[wid] = m;
    __syncthreads();
    if (threadIdx.x == 0) {
        float mm = fmaxf(fmaxf(sm[0], sm[1]), fmaxf(sm[2], sm[3]));
        atomicMax(slots + slot, __float_as_uint(mm));  // f32 bits compare as uint for >=0
    }
}

// ---------------- fused quant: hidden -> hq8, 4 weights -> Wall8 (1MB apart) ------------
__global__ void quant_all(const float* __restrict__ hidden,
                          const float* __restrict__ w0, const float* __restrict__ w1,
                          const float* __restrict__ w2, const float* __restrict__ w3,
                          const float* __restrict__ amax,
                          char* __restrict__ hq8, char* __restrict__ Wall8) {
    const float* x; char* y; int n4, slot, bx, nb;
    if (blockIdx.x < 1024) { x = hidden; y = hq8; n4 = Mm * Dd / 4; slot = 0; bx = blockIdx.x; nb = 1024; }
    else {
        int w = (blockIdx.x - 1024) >> 5; bx = (blockIdx.x - 1024) & 31; nb = 32;
        x = w == 0 ? w0 : w == 1 ? w1 : w == 2 ? w2 : w3;
        y = Wall8 + ((size_t)w << 20);
        n4 = Dd * Dd / 4; slot = 1 + w;
    }
    float s = qscale(amax[slot]);
    const float4* x4 = (const float4*)x;
    char4* y4 = (char4*)y;
    for (int i = bx * blockDim.x + threadIdx.x; i < n4; i += nb * blockDim.x) {
        float4 v = x4[i];
        char4 q;
        q.x = (char)(int)rintf(v.x / s);
        q.y = (char)(int)rintf(v.y / s);
        q.z = (char)(int)rintf(v.z / s);
        q.w = (char)(int)rintf(v.w / s);
        y4[i] = q;
    }
}

// quant attn output (scale inline from amax slot)
__global__ void quant_a(const float* __restrict__ x, char* __restrict__ y,
                        const float* __restrict__ amax, int n4) {
    float s = qscale(amax[0]);
    int stride = gridDim.x * blockDim.x;
    const float4* x4 = (const float4*)x;
    char4* y4 = (char4*)y;
    for (int i = blockIdx.x * blockDim.x + threadIdx.x; i < n4; i += stride) {
        float4 v = x4[i];
        char4 q;
        q.x = (char)(int)rintf(v.x / s);
        q.y = (char)(int)rintf(v.y / s);
        q.z = (char)(int)rintf(v.z / s);
        q.w = (char)(int)rintf(v.w / s);
        y4[i] = q;
    }
}

// ---------------- int8 MFMA GEMM core: 128x128 tile, BK=64, 4 waves of 64x64 ------------
// T3 single-barrier double-buffered staging: stage(s+1 -> buf^1) || compute(buf);
// one __syncthreads per K-step (its implicit vmcnt(0) drain is covered by the MFMA phase).
#define GLOAD_LDS16(g, l) __builtin_amdgcn_global_load_lds( \
    (const __attribute__((address_space(1))) unsigned int*)(g), \
    (__attribute__((address_space(3))) unsigned int*)(l), 16, 0, 0)

__device__ __forceinline__ void gemm128_core(const char* __restrict__ A, const char* __restrict__ Bw,
                                             int bm, int bn, int K, int t,
                                             char* At, char* Bt, v4i acc[4][4]) {
    const int lane = t & 63, w = t >> 6;
    const int wm = (w >> 1) * 64, wn = (w & 1) * 64;
    const int lr = lane & 15, kq = lane >> 4;
    const int rs = w * 16 + (lane >> 2);  // wave-contiguous staged row
    const int cc = lane & 3;
    const int NT = K / 64;

    auto stage = [&](int s, int buf) {
        int k0 = s * 64;
        char* Ab = At + buf * 16384;
        char* Bb = Bt + buf * 16384;
        #pragma unroll
        for (int h = 0; h < 2; h++) {
            int r = rs + h * 64;
            int cs = cc ^ ((r >> 1) & 3);  // source-side XOR swizzle
            GLOAD_LDS16(A  + (size_t)(bm + r) * K + k0 + cs * 16, Ab + r * 64 + cc * 16);
            GLOAD_LDS16(Bw + (size_t)(bn + r) * K + k0 + cs * 16, Bb + r * 64 + cc * 16);
        }
    };

    stage(0, 0);
    __syncthreads();
    for (int s = 0; s < NT; s++) {
        const int cur = s & 1;
        if (s + 1 < NT) stage(s + 1, cur ^ 1);

        const char* Ac = At + cur * 16384;
        const char* Bc = Bt + cur * 16384;
        v4i af[4], bf[4];
        #pragma unroll
        for (int mt = 0; mt < 4; mt++) {
            int row = wm + mt * 16 + lr;
            af[mt] = *(const v4i*)(Ac + row * 64 + ((kq ^ ((row >> 1) & 3)) << 4));
        }
        #pragma unroll
        for (int nt = 0; nt < 4; nt++) {
            int row = wn + nt * 16 + lr;
            bf[nt] = *(const v4i*)(Bc + row * 64 + ((kq ^ ((row >> 1) & 3)) << 4));
        }
        #pragma unroll
        for (int mt = 0; mt < 4; mt++)
            #pragma unroll
            for (int nt = 0; nt < 4; nt++)
                acc[mt][nt] = __builtin_amdgcn_mfma_i32_16x16x64_i8(af[mt], bf[nt], acc[mt][nt], 0, 0, 0);

        if (s + 1 < NT) __syncthreads();  // buf[cur^1] ready; buf[cur] free for s+2
    }
}

// Fused Q/K/V projection with LDS-transpose epilogue (coalesced 16B stores, no write
// amplification). Q: bf16 (pre-scaled by 0.125/ln2); K: bf16; V: bf16 transposed [B,H,64,S].
__global__ __launch_bounds__(256) void gemm_qkv(const char* __restrict__ A,
                                                const char* __restrict__ Wall8,
                                                const float* __restrict__ bq,
                                                const float* __restrict__ bk,
                                                const float* __restrict__ bv,
                                                const float* __restrict__ amax,
                                                unsigned short* __restrict__ qb16,
                                                unsigned short* __restrict__ kb16,
                                                unsigned short* __restrict__ vt16) {
    // k-loop: dbuf At|Bt (2x16KB = 32KB); epilogue: 128x136 ushort (34816B)
    __shared__ alignas(16) char pool[34816];
    char* At = pool;
    char* Bt = pool + 8192;
    unsigned short (*Tt)[136] = (unsigned short(*)[136])pool;

    const int t = threadIdx.x, lane = t & 63, w = t >> 6;
    const int mat = blockIdx.x >> 3;
    const int bn = (blockIdx.x & 7) * 128, bm = blockIdx.y * 128;
    const int wm = (w >> 1) * 64, wn = (w & 1) * 64;
    const int lr = lane & 15, kq = lane >> 4;

    const v4i vzero = {0, 0, 0, 0};
    v4i acc[4][4];
    #pragma unroll
    for (int mt = 0; mt < 4; mt++)
        #pragma unroll
        for (int nt = 0; nt < 4; nt++) acc[mt][nt] = vzero;

    const char* Bw = Wall8 + ((size_t)mat << 20);
    gemm128_core(A, Bw, bm, bn, Dd, t, At, Bt, acc);

    const float* bias = mat == 0 ? bq : mat == 1 ? bk : bv;
    float sc = qscale(amax[0]) * qscale(amax[1 + mat]);
    float pm = (mat == 0) ? QPOSTMUL : 1.0f;

    __syncthreads();  // all waves done reading staging before Tt overwrites the pool

    // ---- phase A: acc -> bf16 -> LDS tile ----
    if (mat != 2) {
        // Tt[m][n] (row-major target)
        #pragma unroll
        for (int nt = 0; nt < 4; nt++) {
            int n_l = wn + nt * 16 + lr;
            float bv_ = bias[bn + n_l];
            #pragma unroll
            for (int mt = 0; mt < 4; mt++) {
                int m_l = wm + mt * 16 + kq * 4;
                #pragma unroll
                for (int rg = 0; rg < 4; rg++)
                    Tt[m_l + rg][n_l] = bf16rtn(((float)acc[mt][nt][rg] * sc + bv_) * pm);
            }
        }
    } else {
        // Tt[n][m] (V^T target): lane's 4 consecutive m -> one 8B write
        #pragma unroll
        for (int nt = 0; nt < 4; nt++) {
            int n_l = wn + nt * 16 + lr;
            float bv_ = bias[bn + n_l];
            #pragma unroll
            for (int mt = 0; mt < 4; mt++) {
                int m_l = wm + mt * 16 + kq * 4;
                ushort4 hv;
                hv.x = bf16rtn((float)acc[mt][nt][0] * sc + bv_);
                hv.y = bf16rtn((float)acc[mt][nt][1] * sc + bv_);
                hv.z = bf16rtn((float)acc[mt][nt][2] * sc + bv_);
                hv.w = bf16rtn((float)acc[mt][nt][3] * sc + bv_);
                *(ushort4*)&Tt[n_l][m_l] = hv;
            }
        }
    }
    __syncthreads();

    // ---- phase B: coalesced 16B stores of contiguous 256B rows ----
    {
        int row = t >> 1, half = t & 1;
        unsigned short* dst;
        if (mat != 2) {
            dst = (mat == 0 ? qb16 : kb16) + (size_t)(bm + row) * Dd + bn + half * 64;
        } else {
            int n = bn + row;
            int e = n & 63, hc = n >> 6;
            int b_ = bm >> 11, s_ = (bm & 2047) + half * 64;
            dst = vt16 + (((size_t)(b_ * Hh + hc) * 64 + e) * Ss) + s_;
        }
        const unsigned short* srcl = &Tt[row][half * 64];
        #pragma unroll
        for (int c = 0; c < 8; c++)
            *(int4*)(dst + c * 8) = *(const int4*)(srcl + c * 8);
    }
}

// O-projection: 128m x 64n tile, dbuf single-barrier k-loop. f32 output.
__global__ __launch_bounds__(256) void gemm_o(const char* __restrict__ A,
                                              const char* __restrict__ Bw,
                                              const float* __restrict__ bias,
                                              const float* __restrict__ amaxA,
                                              const float* __restrict__ amaxB,
                                              float* __restrict__ C) {
    // dbuf: A0@0(8K), B0@8K(4K), A1@12K, B1@20K -> 24576B
    __shared__ alignas(16) char pool[24576];
    const int t = threadIdx.x, lane = t & 63, w = t >> 6;
    const int bn = blockIdx.x * 64, bm = blockIdx.y * 128;
    const int wm = (w >> 1) * 64, wn = (w & 1) * 32;
    const int lr = lane & 15, kq = lane >> 4;
    const int rs = t >> 2, cc = t & 3;
    const int cs = cc ^ ((rs >> 1) & 3);
    const int rs2 = rs + 64, cs2 = cc ^ ((rs2 >> 1) & 3);

    auto stage = [&](int s, int buf) {
        int k0 = s * 64;
        char* Ab = pool + buf * 12288;
        char* Bb = Ab + 8192;
        GLOAD_LDS16(A  + (size_t)(bm + rs)  * Dd + k0 + cs  * 16, Ab + rs  * 64 + cc * 16);
        GLOAD_LDS16(A  + (size_t)(bm + rs2) * Dd + k0 + cs2 * 16, Ab + rs2 * 64 + cc * 16);
        GLOAD_LDS16(Bw + (size_t)(bn + rs)  * Dd + k0 + cs  * 16, Bb + rs  * 64 + cc * 16);
    };

    const v4i vzero = {0, 0, 0, 0};
    v4i acc[4][2];
    #pragma unroll
    for (int mt = 0; mt < 4; mt++) { acc[mt][0] = vzero; acc[mt][1] = vzero; }

    stage(0, 0);
    __syncthreads();
    const int NT = Dd / 64;
    for (int s = 0; s < NT; s++) {
        const int cur = s & 1;
        if (s + 1 < NT) stage(s + 1, cur ^ 1);

        const char* Ac = pool + cur * 12288;
        const char* Bc = Ac + 8192;
        v4i af[4], bf[2];
        #pragma unroll
        for (int mt = 0; mt < 4; mt++) {
            int row = wm + mt * 16 + lr;
            af[mt] = *(const v4i*)(Ac + row * 64 + ((kq ^ ((row >> 1) & 3)) << 4));
        }
        #pragma unroll
        for (int nt = 0; nt < 2; nt++) {
            int row = wn + nt * 16 + lr;
            bf[nt] = *(const v4i*)(Bc + row * 64 + ((kq ^ ((row >> 1) & 3)) << 4));
        }
        #pragma unroll
        for (int mt = 0; mt < 4; mt++)
            #pragma unroll
            for (int nt = 0; nt < 2; nt++)
                acc[mt][nt] = __builtin_amdgcn_mfma_i32_16x16x64_i8(af[mt], bf[nt], acc[mt][nt], 0, 0, 0);

        if (s + 1 < NT) __syncthreads();
    }

    float sc = qscale(amaxA[0]) * qscale(amaxB[0]);
    #pragma unroll
    for (int nt = 0; nt < 2; nt++) {
        int n = bn + wn + nt * 16 + lr;
        float bv_ = bias[n];
        #pragma unroll
        for (int mt = 0; mt < 4; mt++)
            #pragma unroll
            for (int rg = 0; rg < 4; rg++) {
                int m = bm + wm + mt * 16 + kq * 4 + rg;
                C[(size_t)m * Dd + n] = (float)acc[mt][nt][rg] * sc + bv_;
            }
    }
}

// ---------------- MFMA flash attention — swapped-QK + gload_lds dbuf staging -----------
// 512 threads = 2 groups x 4 waves; group g handles keys [g*1024, (g+1)*1024).
// Swapped QK (lane-local P, R2 win). K/V staged via global_load_lds (no VGPR round-trip,
// no reg-staged prefetch -> no spill). K's interleave permute rho and the bank XOR
// swizzle are folded into the per-lane GLOBAL source address (LDS dest stays linear,
// m173 pattern); the ds_read side applies the same XOR. One barrier per tile: its
// vmcnt(0) drain waits on loads issued a full compute-phase (~2000 cyc) earlier.
__global__ __launch_bounds__(512, 4) void attn_mfma(
    const unsigned short* __restrict__ qb16, const unsigned short* __restrict__ kb16,
    const unsigned short* __restrict__ vt16,
    const float* __restrict__ mask, float* __restrict__ Ob, unsigned* __restrict__ amax_out) {
    // K: [group][buf][64][64] ushort = 32KB; V same = 32KB. Epilogue overlays base.
    __shared__ alignas(16) char apool[65536];
    unsigned short (*Ks)[2][64][64] = (unsigned short(*)[2][64][64])apool;
    unsigned short (*Vs)[2][64][64] = (unsigned short(*)[2][64][64])(apool + 32768);
    __shared__ float wred[4];

    const int t = threadIdx.x, lane = t & 63, wq = t >> 6;
    const int g = wq >> 2, wq4 = wq & 3;
    const int ln31 = lane & 31, h5 = lane >> 5;
    const int b = blockIdx.z, h = blockIdx.y, q0 = blockIdx.x * 128;
    const int kbase = g << 10;

    // Q fragments (B operand after swap): q-col = ln31, k = c*16 + h5*8 + j
    bf16x8 qf[4];
    {
        int qrow = q0 + wq4 * 32 + ln31;
        const unsigned short* qb_ = qb16 + ((size_t)(b * Ss + qrow)) * Dd + h * 64 + h5 * 8;
        #pragma unroll
        for (int c = 0; c < 4; c++) qf[c] = *(const bf16x8*)(qb_ + c * 16);
    }

    // gload_lds staging: wave wq4 fills LDS rows [16*wq4, 16*wq4+16) of its group's
    // K and V tiles; per instr 8 rows (64 lanes x 16B). LDS dest = base + 16*lane
    // (linear). Source address carries rho^-1 (K row = 2*(r&31)+(r>>5)) and the
    // chunk XOR swizzle (chunk ^ (r&7), with r&7 == lane>>3).
    auto stageKV = [&](int k0, int buf) {
        #pragma unroll
        for (int i = 0; i < 2; i++) {
            int r = wq4 * 16 + i * 8 + (lane >> 3);
            int sc_ = (lane & 7) ^ (lane >> 3);
            int kr = 2 * (r & 31) + (r >> 5);
            GLOAD_LDS16(kb16 + (size_t)(b * Ss + k0 + kr) * Dd + h * 64 + sc_ * 8,
                        (char*)&Ks[g][buf][r][(lane & 7) * 8]);
            GLOAD_LDS16(vt16 + ((size_t)((b * Hh + h) * 64 + r)) * Ss + k0 + sc_ * 8,
                        (char*)&Vs[g][buf][r][(lane & 7) * 8]);
        }
    };

    f32x16 o0 = 0.f, o1 = 0.f;
    float la0 = 0.f, la1 = 0.f, la2 = 0.f, la3 = 0.f;
    const int swz = ln31 & 7;  // read-side XOR (same for rows r and 32+r)

    constexpr int NT = (Ss / 2) / 64;  // 16 tiles per group
    float pmv = mask[b * Ss + kbase + lane], pmvn = 1.f;
    stageKV(kbase, 0);
    __syncthreads();  // drains the prologue loads; buf0 ready

    for (int it = 0; it < NT; it++) {
        const int cur = it & 1;
        if (it + 1 < NT) {
            stageKV(kbase + (it + 1) * 64, cur ^ 1);  // in flight across the compute phase
            pmvn = mask[b * Ss + kbase + (it + 1) * 64 + lane];
        }
        unsigned long long bm = __ballot(pmv > 0.5f);

        // QK^T SWAPPED: sc = mfma(K, Q). D row = key-in-tile, col = q (ln31).
        // tile0 = even orig keys (LDS rows 0-31), tile1 = odd (rows 32-63).
        f32x16 sc0 = 0.f, sc1 = 0.f;
        __builtin_amdgcn_s_setprio(1);
        #pragma unroll
        for (int c = 0; c < 4; c++) {
            int ch = ((2 * c + h5) ^ swz) * 8;
            bf16x8 kh0 = *(const bf16x8*)&Ks[g][cur][ln31][ch];
            bf16x8 kh1 = *(const bf16x8*)&Ks[g][cur][32 + ln31][ch];
            sc0 = __builtin_amdgcn_mfma_f32_32x32x16_bf16(kh0, qf[c], sc0, 0, 0, 0);
            sc1 = __builtin_amdgcn_mfma_f32_32x32x16_bf16(kh1, qf[c], sc1, 0, 0, 0);
        }
        __builtin_amdgcn_s_setprio(0);

        // Fused softmax + PV per d-chunk c: reg r=4c+j holds keys 16c+8*h5+2j (sc0)
        // and +1 (sc1); PV chunk c consumes exactly those 8 -> in-register A-fragment.
        #pragma unroll
        for (int c = 0; c < 4; c++) {
            float e0[4], e1[4];
            #pragma unroll
            for (int j = 0; j < 4; j++) {
                e0[j] = __builtin_amdgcn_exp2f(sc0[4 * c + j]);
                e1[j] = __builtin_amdgcn_exp2f(sc1[4 * c + j]);
            }
            if (bm != ~0ull) {
                #pragma unroll
                for (int j = 0; j < 4; j++) {
                    int kk = 16 * c + 8 * h5 + 2 * j;
                    e0[j] *= (float)(int)((bm >> kk) & 1);
                    e1[j] *= (float)(int)((bm >> (kk + 1)) & 1);
                }
            }
            la0 += e0[0] + e1[0];
            la1 += e0[1] + e1[1];
            la2 += e0[2] + e1[2];
            la3 += e0[3] + e1[3];

            uint4 pw;
            pw.x = pack_bf16x2(e0[0], e1[0]);
            pw.y = pack_bf16x2(e0[1], e1[1]);
            pw.z = pack_bf16x2(e0[2], e1[2]);
            pw.w = pack_bf16x2(e0[3], e1[3]);
            bf16x8 pf = __builtin_bit_cast(bf16x8, pw);
            int ch = ((2 * c + h5) ^ swz) * 8;
            bf16x8 vh0 = *(const bf16x8*)&Vs[g][cur][ln31][ch];
            bf16x8 vh1 = *(const bf16x8*)&Vs[g][cur][32 + ln31][ch];
            __builtin_amdgcn_s_setprio(1);
            o0 = __builtin_amdgcn_mfma_f32_32x32x16_bf16(pf, vh0, o0, 0, 0, 0);
            o1 = __builtin_amdgcn_mfma_f32_32x32x16_bf16(pf, vh1, o1, 0, 0, 0);
            __builtin_amdgcn_s_setprio(0);
        }
        pmv = pmvn;
        __syncthreads();  // next buf ready (vmcnt drain); cur reusable next iter
    }

    // ---- combine epilogue: O = (O_g0 + O_g1) / (l_g0 + l_g1) ----
    // lane's l covers its h5-half's 32 keys/tile; pair-sum across halves (same q).
    float lsum = (la0 + la1) + (la2 + la3);
    lsum += __shfl_xor(lsum, 32, 64);

    __syncthreads();  // all K/V staging reads done; safe to overlay on apool
    float (*Osh)[65] = (float(*)[65])apool;               // 128*65*4 = 33280B
    float (*Lsh2)[128] = (float(*)[128])(apool + 33280);  // [2][128] f32, 1024B

    if (lane < 32) Lsh2[g][wq4 * 32 + ln31] = lsum;  // per-q-row l partial for this group
    if (g == 1) {
        #pragma unroll
        for (int r = 0; r < 16; r++) {
            int rl = wq4 * 32 + (r & 3) + 8 * (r >> 2) + 4 * h5;
            Osh[rl][ln31]      = o0[r];
            Osh[rl][32 + ln31] = o1[r];
        }
    }
    __syncthreads();
    if (g == 0) {
        float lmax = 0.f;
        #pragma unroll
        for (int r = 0; r < 16; r++) {
            int rl = wq4 * 32 + (r & 3) + 8 * (r >> 2) + 4 * h5;
            float inv = 1.0f / (Lsh2[0][rl] + Lsh2[1][rl]);
            size_t ro = ((size_t)(b * Ss + q0 + rl)) * Dd + h * 64;
            float v0 = (o0[r] + Osh[rl][ln31]) * inv;
            float v1 = (o1[r] + Osh[rl][32 + ln31]) * inv;
            Ob[ro + ln31]      = v0;
            Ob[ro + 32 + ln31] = v1;
            lmax = fmaxf(lmax, fmaxf(fabsf(v0), fabsf(v1)));
        }
        #pragma unroll
        for (int off = 32; off > 0; off >>= 1) lmax = fmaxf(lmax, __shfl_xor(lmax, off, 64));
        if (lane == 0) wred[wq4] = lmax;
    }
    __syncthreads();
    if (t == 0) {
        float m = fmaxf(fmaxf(wred[0], wred[1]), fmaxf(wred[2], wred[3]));
        atomicMax(amax_out, __float_as_uint(m));
    }
}

// ---------------- launch ----------------
extern "C" void kernel_launch(void* const* d_in, const int* in_sizes, int n_in,
                              void* d_out, int out_size, void* d_ws, size_t ws_size,
                              hipStream_t stream) {
    const float* hidden = (const float*)d_in[0];
    const float* mask   = (const float*)d_in[1];
    const float* Wq = (const float*)d_in[2];
    const float* bq = (const float*)d_in[3];
    const float* Wk = (const float*)d_in[4];
    const float* bk = (const float*)d_in[5];
    const float* Wv = (const float*)d_in[6];
    const float* bv = (const float*)d_in[7];
    const float* Wo = (const float*)d_in[8];
    const float* bo = (const float*)d_in[9];
    float* out = (float*)d_out;

    char* ws = (char*)d_ws;
    float* scal = (float*)ws;  // amax slots 0..5
    size_t off = 1024;
    const size_t szH8 = (size_t)Mm * Dd;                           // 4 MB
    const size_t szHb = (size_t)Mm * Dd * sizeof(unsigned short);  // 8.39 MB
    const size_t szHf = (size_t)Mm * Dd * sizeof(float);           // 16.78 MB
    char* hq8   = ws + off; off += szH8;
    char* Wall8 = ws + off; off += 4u << 20;  // Wq|Wk|Wv|Wo, 1MB each
    char* aq8   = ws + off; off += szH8;
    unsigned short* qb16 = (unsigned short*)(ws + off); off += szHb;
    unsigned short* kb16 = (unsigned short*)(ws + off); off += szHb;
    unsigned short* vt16 = (unsigned short*)(ws + off); off += szHb;
    float* ab = (float*)(ws + off); off += szHf;

    hipMemsetAsync(scal, 0, 64, stream);

    amax_all<<<512, 256, 0, stream>>>((const float4*)hidden, (const float4*)Wq,
                                      (const float4*)Wk, (const float4*)Wv, (const float4*)Wo,
                                      (unsigned*)scal);
    quant_all<<<1152, 256, 0, stream>>>(hidden, Wq, Wk, Wv, Wo, scal, hq8, Wall8);

    gemm_qkv<<<dim3(24, 32), 256, 0, stream>>>(hq8, Wall8, bq, bk, bv, scal,
                                               qb16, kb16, vt16);

    attn_mfma<<<dim3(Ss / 128, Hh, Bb), 512, 0, stream>>>(qb16, kb16, vt16,
                                                          mask, ab, (unsigned*)(scal + 5));

    quant_a<<<1024, 256, 0, stream>>>(ab, aq8, scal + 5, Mm * Dd / 4);

    gemm_o<<<dim3(16, 32), 256, 0, stream>>>(aq8, Wall8 + (3u << 20), bo,
                                             scal + 5, scal + 4, out);
}

// Round 7
// 215.112 us; speedup vs baseline: 1.0634x; 1.0634x over previous
//
#include <hip/hip_runtime.h>
#include <cstddef>
#include <cstdint>

// Problem constants (B=2, S=2048, D=1024, H=16, hd=64)
constexpr int Bb = 2, Ss = 2048, Dd = 1024, Hh = 16, HD = 64;
constexpr int Mm = Bb * Ss;  // 4096 rows

typedef int v4i __attribute__((ext_vector_type(4)));
typedef __bf16 bf16x8 __attribute__((ext_vector_type(8)));
typedef __bf16 bf16x2 __attribute__((ext_vector_type(2)));
typedef float f32x16 __attribute__((ext_vector_type(16)));

// ln2 folding: q *= 0.125 * 1/ln2 so p = exp2(score) is one v_exp_f32
#define QPOSTMUL 0.18033688f

__device__ __forceinline__ float qscale(float amax) {
    return fmaxf(amax / 127.0f, 1e-8f);
}

// round-to-nearest-even f32 -> bf16 bits
__device__ __forceinline__ unsigned short bf16rtn(float x) {
    __bf16 b = (__bf16)x;
    return __builtin_bit_cast(unsigned short, b);
}

// pack two f32 -> bf16x2 in one u32 (compiler emits v_cvt_pk_bf16_f32)
__device__ __forceinline__ unsigned pack_bf16x2(float a, float b) {
    bf16x2 h;
    h[0] = (__bf16)a;
    h[1] = (__bf16)b;
    return __builtin_bit_cast(unsigned, h);
}

// ---------------- fused amax: hidden (slot0) + 4 weights (slots 1-4) ----------------
__global__ void amax_all(const float4* __restrict__ hidden,
                         const float4* __restrict__ w0, const float4* __restrict__ w1,
                         const float4* __restrict__ w2, const float4* __restrict__ w3,
                         unsigned* __restrict__ slots) {
    const float4* src; int n4, slot, bx, nb;
    if (blockIdx.x < 448) { src = hidden; n4 = Mm * Dd / 4; slot = 0; bx = blockIdx.x; nb = 448; }
    else {
        int w = (blockIdx.x - 448) >> 4; bx = (blockIdx.x - 448) & 15; nb = 16;
        src = w == 0 ? w0 : w == 1 ? w1 : w == 2 ? w2 : w3;
        n4 = Dd * Dd / 4; slot = 1 + w;
    }
    float m = 0.f;
    for (int i = bx * blockDim.x + threadIdx.x; i < n4; i += nb * blockDim.x) {
        float4 v = src[i];
        m = fmaxf(m, fmaxf(fmaxf(fabsf(v.x), fabsf(v.y)), fmaxf(fabsf(v.z), fabsf(v.w))));
    }
    #pragma unroll
    for (int off = 32; off > 0; off >>= 1) m = fmaxf(m, __shfl_down(m, off, 64));
    __shared__ float sm[4];
    int lane = threadIdx.x & 63, wid = threadIdx.x >> 6;
    if (lane == 0) sm[wid] = m;
    __syncthreads();
    if (threadIdx.x == 0) {
        float mm = fmaxf(fmaxf(sm[0], sm[1]), fmaxf(sm[2], sm[3]));
        atomicMax(slots + slot, __float_as_uint(mm));  // f32 bits compare as uint for >=0
    }
}

// ---------------- fused quant: hidden -> hq8, 4 weights -> Wall8 (1MB apart) ------------
__global__ void quant_all(const float* __restrict__ hidden,
                          const float* __restrict__ w0, const float* __restrict__ w1,
                          const float* __restrict__ w2, const float* __restrict__ w3,
                          const float* __restrict__ amax,
                          char* __restrict__ hq8, char* __restrict__ Wall8) {
    const float* x; char* y; int n4, slot, bx, nb;
    if (blockIdx.x < 1024) { x = hidden; y = hq8; n4 = Mm * Dd / 4; slot = 0; bx = blockIdx.x; nb = 1024; }
    else {
        int w = (blockIdx.x - 1024) >> 5; bx = (blockIdx.x - 1024) & 31; nb = 32;
        x = w == 0 ? w0 : w == 1 ? w1 : w == 2 ? w2 : w3;
        y = Wall8 + ((size_t)w << 20);
        n4 = Dd * Dd / 4; slot = 1 + w;
    }
    float s = qscale(amax[slot]);
    const float4* x4 = (const float4*)x;
    char4* y4 = (char4*)y;
    for (int i = bx * blockDim.x + threadIdx.x; i < n4; i += nb * blockDim.x) {
        float4 v = x4[i];
        char4 q;
        q.x = (char)(int)rintf(v.x / s);
        q.y = (char)(int)rintf(v.y / s);
        q.z = (char)(int)rintf(v.z / s);
        q.w = (char)(int)rintf(v.w / s);
        y4[i] = q;
    }
}

// quant attn output (scale inline from amax slot)
__global__ void quant_a(const float* __restrict__ x, char* __restrict__ y,
                        const float* __restrict__ amax, int n4) {
    float s = qscale(amax[0]);
    int stride = gridDim.x * blockDim.x;
    const float4* x4 = (const float4*)x;
    char4* y4 = (char4*)y;
    for (int i = blockIdx.x * blockDim.x + threadIdx.x; i < n4; i += stride) {
        float4 v = x4[i];
        char4 q;
        q.x = (char)(int)rintf(v.x / s);
        q.y = (char)(int)rintf(v.y / s);
        q.z = (char)(int)rintf(v.z / s);
        q.w = (char)(int)rintf(v.w / s);
        y4[i] = q;
    }
}

// ---------------- int8 MFMA GEMM core: 128x128 tile, BK=64, 4 waves of 64x64 ------------
// T3 single-barrier double-buffered staging: stage(s+1 -> buf^1) || compute(buf);
// one __syncthreads per K-step (its implicit vmcnt(0) drain is covered by the MFMA phase).
#define GLOAD_LDS16(g, l) __builtin_amdgcn_global_load_lds( \
    (const __attribute__((address_space(1))) unsigned int*)(g), \
    (__attribute__((address_space(3))) unsigned int*)(l), 16, 0, 0)

__device__ __forceinline__ void gemm128_core(const char* __restrict__ A, const char* __restrict__ Bw,
                                             int bm, int bn, int K, int t,
                                             char* At, char* Bt, v4i acc[4][4]) {
    const int lane = t & 63, w = t >> 6;
    const int wm = (w >> 1) * 64, wn = (w & 1) * 64;
    const int lr = lane & 15, kq = lane >> 4;
    const int rs = w * 16 + (lane >> 2);  // wave-contiguous staged row
    const int cc = lane & 3;
    const int NT = K / 64;

    auto stage = [&](int s, int buf) {
        int k0 = s * 64;
        char* Ab = At + buf * 16384;
        char* Bb = Bt + buf * 16384;
        #pragma unroll
        for (int h = 0; h < 2; h++) {
            int r = rs + h * 64;
            int cs = cc ^ ((r >> 1) & 3);  // source-side XOR swizzle
            GLOAD_LDS16(A  + (size_t)(bm + r) * K + k0 + cs * 16, Ab + r * 64 + cc * 16);
            GLOAD_LDS16(Bw + (size_t)(bn + r) * K + k0 + cs * 16, Bb + r * 64 + cc * 16);
        }
    };

    stage(0, 0);
    __syncthreads();
    for (int s = 0; s < NT; s++) {
        const int cur = s & 1;
        if (s + 1 < NT) stage(s + 1, cur ^ 1);

        const char* Ac = At + cur * 16384;
        const char* Bc = Bt + cur * 16384;
        v4i af[4], bf[4];
        #pragma unroll
        for (int mt = 0; mt < 4; mt++) {
            int row = wm + mt * 16 + lr;
            af[mt] = *(const v4i*)(Ac + row * 64 + ((kq ^ ((row >> 1) & 3)) << 4));
        }
        #pragma unroll
        for (int nt = 0; nt < 4; nt++) {
            int row = wn + nt * 16 + lr;
            bf[nt] = *(const v4i*)(Bc + row * 64 + ((kq ^ ((row >> 1) & 3)) << 4));
        }
        #pragma unroll
        for (int mt = 0; mt < 4; mt++)
            #pragma unroll
            for (int nt = 0; nt < 4; nt++)
                acc[mt][nt] = __builtin_amdgcn_mfma_i32_16x16x64_i8(af[mt], bf[nt], acc[mt][nt], 0, 0, 0);

        if (s + 1 < NT) __syncthreads();  // buf[cur^1] ready; buf[cur] free for s+2
    }
}

// Fused Q/K/V projection with LDS-transpose epilogue (coalesced 16B stores, no write
// amplification). Q: bf16 (pre-scaled by 0.125/ln2); K: bf16; V: bf16 transposed [B,H,64,S].
__global__ __launch_bounds__(256) void gemm_qkv(const char* __restrict__ A,
                                                const char* __restrict__ Wall8,
                                                const float* __restrict__ bq,
                                                const float* __restrict__ bk,
                                                const float* __restrict__ bv,
                                                const float* __restrict__ amax,
                                                unsigned short* __restrict__ qb16,
                                                unsigned short* __restrict__ kb16,
                                                unsigned short* __restrict__ vt16) {
    // k-loop: dbuf At|Bt (2x16KB = 32KB); epilogue: 128x136 ushort (34816B)
    __shared__ alignas(16) char pool[34816];
    char* At = pool;
    char* Bt = pool + 8192;
    unsigned short (*Tt)[136] = (unsigned short(*)[136])pool;

    const int t = threadIdx.x, lane = t & 63, w = t >> 6;
    const int mat = blockIdx.x >> 3;
    const int bn = (blockIdx.x & 7) * 128, bm = blockIdx.y * 128;
    const int wm = (w >> 1) * 64, wn = (w & 1) * 64;
    const int lr = lane & 15, kq = lane >> 4;

    const v4i vzero = {0, 0, 0, 0};
    v4i acc[4][4];
    #pragma unroll
    for (int mt = 0; mt < 4; mt++)
        #pragma unroll
        for (int nt = 0; nt < 4; nt++) acc[mt][nt] = vzero;

    const char* Bw = Wall8 + ((size_t)mat << 20);
    gemm128_core(A, Bw, bm, bn, Dd, t, At, Bt, acc);

    const float* bias = mat == 0 ? bq : mat == 1 ? bk : bv;
    float sc = qscale(amax[0]) * qscale(amax[1 + mat]);
    float pm = (mat == 0) ? QPOSTMUL : 1.0f;

    __syncthreads();  // all waves done reading staging before Tt overwrites the pool

    // ---- phase A: acc -> bf16 -> LDS tile ----
    if (mat != 2) {
        // Tt[m][n] (row-major target)
        #pragma unroll
        for (int nt = 0; nt < 4; nt++) {
            int n_l = wn + nt * 16 + lr;
            float bv_ = bias[bn + n_l];
            #pragma unroll
            for (int mt = 0; mt < 4; mt++) {
                int m_l = wm + mt * 16 + kq * 4;
                #pragma unroll
                for (int rg = 0; rg < 4; rg++)
                    Tt[m_l + rg][n_l] = bf16rtn(((float)acc[mt][nt][rg] * sc + bv_) * pm);
            }
        }
    } else {
        // Tt[n][m] (V^T target): lane's 4 consecutive m -> one 8B write
        #pragma unroll
        for (int nt = 0; nt < 4; nt++) {
            int n_l = wn + nt * 16 + lr;
            float bv_ = bias[bn + n_l];
            #pragma unroll
            for (int mt = 0; mt < 4; mt++) {
                int m_l = wm + mt * 16 + kq * 4;
                ushort4 hv;
                hv.x = bf16rtn((float)acc[mt][nt][0] * sc + bv_);
                hv.y = bf16rtn((float)acc[mt][nt][1] * sc + bv_);
                hv.z = bf16rtn((float)acc[mt][nt][2] * sc + bv_);
                hv.w = bf16rtn((float)acc[mt][nt][3] * sc + bv_);
                *(ushort4*)&Tt[n_l][m_l] = hv;
            }
        }
    }
    __syncthreads();

    // ---- phase B: coalesced 16B stores of contiguous 256B rows ----
    {
        int row = t >> 1, half = t & 1;
        unsigned short* dst;
        if (mat != 2) {
            dst = (mat == 0 ? qb16 : kb16) + (size_t)(bm + row) * Dd + bn + half * 64;
        } else {
            int n = bn + row;
            int e = n & 63, hc = n >> 6;
            int b_ = bm >> 11, s_ = (bm & 2047) + half * 64;
            dst = vt16 + (((size_t)(b_ * Hh + hc) * 64 + e) * Ss) + s_;
        }
        const unsigned short* srcl = &Tt[row][half * 64];
        #pragma unroll
        for (int c = 0; c < 8; c++)
            *(int4*)(dst + c * 8) = *(const int4*)(srcl + c * 8);
    }
}

// O-projection: 128m x 64n tile, dbuf single-barrier k-loop. f32 output.
__global__ __launch_bounds__(256) void gemm_o(const char* __restrict__ A,
                                              const char* __restrict__ Bw,
                                              const float* __restrict__ bias,
                                              const float* __restrict__ amaxA,
                                              const float* __restrict__ amaxB,
                                              float* __restrict__ C) {
    // dbuf: A0@0(8K), B0@8K(4K), A1@12K, B1@20K -> 24576B
    __shared__ alignas(16) char pool[24576];
    const int t = threadIdx.x, lane = t & 63, w = t >> 6;
    const int bn = blockIdx.x * 64, bm = blockIdx.y * 128;
    const int wm = (w >> 1) * 64, wn = (w & 1) * 32;
    const int lr = lane & 15, kq = lane >> 4;
    const int rs = t >> 2, cc = t & 3;
    const int cs = cc ^ ((rs >> 1) & 3);
    const int rs2 = rs + 64, cs2 = cc ^ ((rs2 >> 1) & 3);

    auto stage = [&](int s, int buf) {
        int k0 = s * 64;
        char* Ab = pool + buf * 12288;
        char* Bb = Ab + 8192;
        GLOAD_LDS16(A  + (size_t)(bm + rs)  * Dd + k0 + cs  * 16, Ab + rs  * 64 + cc * 16);
        GLOAD_LDS16(A  + (size_t)(bm + rs2) * Dd + k0 + cs2 * 16, Ab + rs2 * 64 + cc * 16);
        GLOAD_LDS16(Bw + (size_t)(bn + rs)  * Dd + k0 + cs  * 16, Bb + rs  * 64 + cc * 16);
    };

    const v4i vzero = {0, 0, 0, 0};
    v4i acc[4][2];
    #pragma unroll
    for (int mt = 0; mt < 4; mt++) { acc[mt][0] = vzero; acc[mt][1] = vzero; }

    stage(0, 0);
    __syncthreads();
    const int NT = Dd / 64;
    for (int s = 0; s < NT; s++) {
        const int cur = s & 1;
        if (s + 1 < NT) stage(s + 1, cur ^ 1);

        const char* Ac = pool + cur * 12288;
        const char* Bc = Ac + 8192;
        v4i af[4], bf[2];
        #pragma unroll
        for (int mt = 0; mt < 4; mt++) {
            int row = wm + mt * 16 + lr;
            af[mt] = *(const v4i*)(Ac + row * 64 + ((kq ^ ((row >> 1) & 3)) << 4));
        }
        #pragma unroll
        for (int nt = 0; nt < 2; nt++) {
            int row = wn + nt * 16 + lr;
            bf[nt] = *(const v4i*)(Bc + row * 64 + ((kq ^ ((row >> 1) & 3)) << 4));
        }
        #pragma unroll
        for (int mt = 0; mt < 4; mt++)
            #pragma unroll
            for (int nt = 0; nt < 2; nt++)
                acc[mt][nt] = __builtin_amdgcn_mfma_i32_16x16x64_i8(af[mt], bf[nt], acc[mt][nt], 0, 0, 0);

        if (s + 1 < NT) __syncthreads();
    }

    float sc = qscale(amaxA[0]) * qscale(amaxB[0]);
    #pragma unroll
    for (int nt = 0; nt < 2; nt++) {
        int n = bn + wn + nt * 16 + lr;
        float bv_ = bias[n];
        #pragma unroll
        for (int mt = 0; mt < 4; mt++)
            #pragma unroll
            for (int rg = 0; rg < 4; rg++) {
                int m = bm + wm + mt * 16 + kq * 4 + rg;
                C[(size_t)m * Dd + n] = (float)acc[mt][nt][rg] * sc + bv_;
            }
    }
}

// ---------------- MFMA flash attention — swapped-QK, lane-local P (R3 = 56.1 µs) -------
// 512 threads = 2 groups x 4 waves; group g handles keys [g*1024, (g+1)*1024).
// QK^T computed SWAPPED: sc = mfma(K, Q) -> lane ln31 holds P[q=ln31][64 keys] in regs.
// With the even/odd K interleave, PV chunk c needs exactly keys 16c+8*h5+{0..7} =
// the lane's own {p0,p1}[4c..4c+3] -> A-fragment assembled in-register; no P LDS
// round-trip. Softmax+PV fused per d-chunk to cap VGPR liveness under (512,4)'s 128.
// Simple 2-barrier tile schedule + reg prefetch — measured faster than both dbuf
// restructurings (R4: reg-dbuf, R5: gload_lds), which blew up WRITE_SIZE/conflicts.
__global__ __launch_bounds__(512, 4) void attn_mfma(
    const unsigned short* __restrict__ qb16, const unsigned short* __restrict__ kb16,
    const unsigned short* __restrict__ vt16,
    const float* __restrict__ mask, float* __restrict__ Ob, unsigned* __restrict__ amax_out) {
    // K/V staging for both groups (36864B); overlaid by Osh[128][65]+Lsh2 in epilogue
    __shared__ alignas(16) char apool[36864];
    unsigned short (*Ks)[64][72] = (unsigned short(*)[64][72])apool;             // [2][64][72]
    unsigned short (*Vs)[64][72] = (unsigned short(*)[64][72])(apool + 18432);   // [2][64][72]
    __shared__ float wred[4];

    const int t = threadIdx.x, lane = t & 63, wq = t >> 6;
    const int g = wq >> 2, wq4 = wq & 3, tg = t & 255;
    const int ln31 = lane & 31, h5 = lane >> 5;
    const int b = blockIdx.z, h = blockIdx.y, q0 = blockIdx.x * 128;
    const int kbase = g << 10;

    // Q fragments (B operand after swap): q-col = ln31, k = c*16 + h5*8 + j
    bf16x8 qf[4];
    {
        int qrow = q0 + wq4 * 32 + ln31;
        const unsigned short* qb_ = qb16 + ((size_t)(b * Ss + qrow)) * Dd + h * 64 + h5 * 8;
        #pragma unroll
        for (int c = 0; c < 4; c++) qf[c] = *(const bf16x8*)(qb_ + c * 16);
    }

    const int srow = tg >> 2, cp = (tg & 3) * 2;
    const int rho = (srow >> 1) + (srow & 1) * 32;  // interleave permute for K
    int4 pk0, pk1, pv0, pv1; float pmv = 1.f;
    auto prefetch = [&](int k0) {
        const unsigned short* gk = kb16 + ((size_t)(b * Ss + k0 + srow)) * Dd + h * 64 + cp * 8;
        const unsigned short* gv = vt16 + (((size_t)(b * Hh + h) * 64 + srow)) * Ss + k0 + cp * 8;
        pk0 = *(const int4*)gk; pk1 = *(const int4*)(gk + 8);
        pv0 = *(const int4*)gv; pv1 = *(const int4*)(gv + 8);
        pmv = mask[b * Ss + k0 + lane];  // per-wave copy of the tile's 64 mask values
    };

    f32x16 o0 = 0.f, o1 = 0.f;
    float la0 = 0.f, la1 = 0.f, la2 = 0.f, la3 = 0.f;

    prefetch(kbase);
    for (int k0 = kbase; k0 < kbase + Ss / 2; k0 += 64) {
        __syncthreads();
        *(int4*)&Ks[g][rho][cp * 8]      = pk0;
        *(int4*)&Ks[g][rho][cp * 8 + 8]  = pk1;
        *(int4*)&Vs[g][srow][cp * 8]     = pv0;
        *(int4*)&Vs[g][srow][cp * 8 + 8] = pv1;
        unsigned long long bm = __ballot(pmv > 0.5f);
        __syncthreads();
        if (k0 + 64 < kbase + Ss / 2) prefetch(k0 + 64);  // in flight during MFMA phase

        // QK^T SWAPPED: sc = mfma(K, Q). D row = key-in-tile, col = q (ln31).
        // tile0 = even orig keys (staged rows 0-31), tile1 = odd (rows 32-63).
        f32x16 sc0 = 0.f, sc1 = 0.f;
        __builtin_amdgcn_s_setprio(1);
        #pragma unroll
        for (int c = 0; c < 4; c++) {
            bf16x8 kh0 = *(const bf16x8*)&Ks[g][ln31][c * 16 + h5 * 8];
            bf16x8 kh1 = *(const bf16x8*)&Ks[g][32 + ln31][c * 16 + h5 * 8];
            sc0 = __builtin_amdgcn_mfma_f32_32x32x16_bf16(kh0, qf[c], sc0, 0, 0, 0);
            sc1 = __builtin_amdgcn_mfma_f32_32x32x16_bf16(kh1, qf[c], sc1, 0, 0, 0);
        }
        __builtin_amdgcn_s_setprio(0);

        // Fused softmax + PV per d-chunk c: reg r=4c+j holds keys 16c+8*h5+2j (sc0)
        // and +1 (sc1); PV chunk c consumes exactly those 8 -> in-register A-fragment.
        #pragma unroll
        for (int c = 0; c < 4; c++) {
            float e0[4], e1[4];
            #pragma unroll
            for (int j = 0; j < 4; j++) {
                e0[j] = __builtin_amdgcn_exp2f(sc0[4 * c + j]);
                e1[j] = __builtin_amdgcn_exp2f(sc1[4 * c + j]);
            }
            if (bm != ~0ull) {
                #pragma unroll
                for (int j = 0; j < 4; j++) {
                    int kk = 16 * c + 8 * h5 + 2 * j;
                    e0[j] *= (float)(int)((bm >> kk) & 1);
                    e1[j] *= (float)(int)((bm >> (kk + 1)) & 1);
                }
            }
            la0 += e0[0] + e1[0];
            la1 += e0[1] + e1[1];
            la2 += e0[2] + e1[2];
            la3 += e0[3] + e1[3];

            uint4 pw;
            pw.x = pack_bf16x2(e0[0], e1[0]);
            pw.y = pack_bf16x2(e0[1], e1[1]);
            pw.z = pack_bf16x2(e0[2], e1[2]);
            pw.w = pack_bf16x2(e0[3], e1[3]);
            bf16x8 pf = __builtin_bit_cast(bf16x8, pw);
            bf16x8 vh0 = *(const bf16x8*)&Vs[g][ln31][c * 16 + h5 * 8];
            bf16x8 vh1 = *(const bf16x8*)&Vs[g][32 + ln31][c * 16 + h5 * 8];
            __builtin_amdgcn_s_setprio(1);
            o0 = __builtin_amdgcn_mfma_f32_32x32x16_bf16(pf, vh0, o0, 0, 0, 0);
            o1 = __builtin_amdgcn_mfma_f32_32x32x16_bf16(pf, vh1, o1, 0, 0, 0);
            __builtin_amdgcn_s_setprio(0);
        }
    }

    // ---- combine epilogue: O = (O_g0 + O_g1) / (l_g0 + l_g1) ----
    // lane's l covers its h5-half's 32 keys/tile; pair-sum across halves (same q).
    float lsum = (la0 + la1) + (la2 + la3);
    lsum += __shfl_xor(lsum, 32, 64);

    __syncthreads();  // all K/V staging reads done; safe to overlay on apool
    float (*Osh)[65] = (float(*)[65])apool;               // 128*65*4 = 33280B
    float (*Lsh2)[128] = (float(*)[128])(apool + 33280);  // [2][128] f32, 1024B

    if (lane < 32) Lsh2[g][wq4 * 32 + ln31] = lsum;  // per-q-row l partial for this group
    if (g == 1) {
        #pragma unroll
        for (int r = 0; r < 16; r++) {
            int rl = wq4 * 32 + (r & 3) + 8 * (r >> 2) + 4 * h5;
            Osh[rl][ln31]      = o0[r];
            Osh[rl][32 + ln31] = o1[r];
        }
    }
    __syncthreads();
    if (g == 0) {
        float lmax = 0.f;
        #pragma unroll
        for (int r = 0; r < 16; r++) {
            int rl = wq4 * 32 + (r & 3) + 8 * (r >> 2) + 4 * h5;
            float inv = 1.0f / (Lsh2[0][rl] + Lsh2[1][rl]);
            size_t ro = ((size_t)(b * Ss + q0 + rl)) * Dd + h * 64;
            float v0 = (o0[r] + Osh[rl][ln31]) * inv;
            float v1 = (o1[r] + Osh[rl][32 + ln31]) * inv;
            Ob[ro + ln31]      = v0;
            Ob[ro + 32 + ln31] = v1;
            lmax = fmaxf(lmax, fmaxf(fabsf(v0), fabsf(v1)));
        }
        #pragma unroll
        for (int off = 32; off > 0; off >>= 1) lmax = fmaxf(lmax, __shfl_xor(lmax, off, 64));
        if (lane == 0) wred[wq4] = lmax;
    }
    __syncthreads();
    if (t == 0) {
        float m = fmaxf(fmaxf(wred[0], wred[1]), fmaxf(wred[2], wred[3]));
        atomicMax(amax_out, __float_as_uint(m));
    }
}

// ---------------- launch ----------------
extern "C" void kernel_launch(void* const* d_in, const int* in_sizes, int n_in,
                              void* d_out, int out_size, void* d_ws, size_t ws_size,
                              hipStream_t stream) {
    const float* hidden = (const float*)d_in[0];
    const float* mask   = (const float*)d_in[1];
    const float* Wq = (const float*)d_in[2];
    const float* bq = (const float*)d_in[3];
    const float* Wk = (const float*)d_in[4];
    const float* bk = (const float*)d_in[5];
    const float* Wv = (const float*)d_in[6];
    const float* bv = (const float*)d_in[7];
    const float* Wo = (const float*)d_in[8];
    const float* bo = (const float*)d_in[9];
    float* out = (float*)d_out;

    char* ws = (char*)d_ws;
    float* scal = (float*)ws;  // amax slots 0..5
    size_t off = 1024;
    const size_t szH8 = (size_t)Mm * Dd;                           // 4 MB
    const size_t szHb = (size_t)Mm * Dd * sizeof(unsigned short);  // 8.39 MB
    const size_t szHf = (size_t)Mm * Dd * sizeof(float);           // 16.78 MB
    char* hq8   = ws + off; off += szH8;
    char* Wall8 = ws + off; off += 4u << 20;  // Wq|Wk|Wv|Wo, 1MB each
    char* aq8   = ws + off; off += szH8;
    unsigned short* qb16 = (unsigned short*)(ws + off); off += szHb;
    unsigned short* kb16 = (unsigned short*)(ws + off); off += szHb;
    unsigned short* vt16 = (unsigned short*)(ws + off); off += szHb;
    float* ab = (float*)(ws + off); off += szHf;

    hipMemsetAsync(scal, 0, 64, stream);

    amax_all<<<512, 256, 0, stream>>>((const float4*)hidden, (const float4*)Wq,
                                      (const float4*)Wk, (const float4*)Wv, (const float4*)Wo,
                                      (unsigned*)scal);
    quant_all<<<1152, 256, 0, stream>>>(hidden, Wq, Wk, Wv, Wo, scal, hq8, Wall8);

    gemm_qkv<<<dim3(24, 32), 256, 0, stream>>>(hq8, Wall8, bq, bk, bv, scal,
                                               qb16, kb16, vt16);

    attn_mfma<<<dim3(Ss / 128, Hh, Bb), 512, 0, stream>>>(qb16, kb16, vt16,
                                                          mask, ab, (unsigned*)(scal + 5));

    quant_a<<<1024, 256, 0, stream>>>(ab, aq8, scal + 5, Mm * Dd / 4);

    gemm_o<<<dim3(16, 32), 256, 0, stream>>>(aq8, Wall8 + (3u << 20), bo,
                                             scal + 5, scal + 4, out);
}

// Round 8
// 212.665 us; speedup vs baseline: 1.0757x; 1.0115x over previous
//
#include <hip/hip_runtime.h>
#include <cstddef>
#include <cstdint>

// Problem constants (B=2, S=2048, D=1024, H=16, hd=64)
constexpr int Bb = 2, Ss = 2048, Dd = 1024, Hh = 16, HD = 64;
constexpr int Mm = Bb * Ss;  // 4096 rows

typedef int v4i __attribute__((ext_vector_type(4)));
typedef __bf16 bf16x8 __attribute__((ext_vector_type(8)));
typedef __bf16 bf16x2 __attribute__((ext_vector_type(2)));
typedef float f32x16 __attribute__((ext_vector_type(16)));

// ln2 folding: q *= 0.125 * 1/ln2 so p = exp2(score) is one v_exp_f32
#define QPOSTMUL 0.18033688f

__device__ __forceinline__ float qscale(float amax) {
    return fmaxf(amax / 127.0f, 1e-8f);
}

// round-to-nearest-even f32 -> bf16 bits
__device__ __forceinline__ unsigned short bf16rtn(float x) {
    __bf16 b = (__bf16)x;
    return __builtin_bit_cast(unsigned short, b);
}

// pack two f32 -> bf16x2 in one u32 (compiler emits v_cvt_pk_bf16_f32)
__device__ __forceinline__ unsigned pack_bf16x2(float a, float b) {
    bf16x2 h;
    h[0] = (__bf16)a;
    h[1] = (__bf16)b;
    return __builtin_bit_cast(unsigned, h);
}

// ---------------- fused amax: hidden (slot0) + 4 weights (slots 1-4) ----------------
__global__ void amax_all(const float4* __restrict__ hidden,
                         const float4* __restrict__ w0, const float4* __restrict__ w1,
                         const float4* __restrict__ w2, const float4* __restrict__ w3,
                         unsigned* __restrict__ slots) {
    const float4* src; int n4, slot, bx, nb;
    if (blockIdx.x < 448) { src = hidden; n4 = Mm * Dd / 4; slot = 0; bx = blockIdx.x; nb = 448; }
    else {
        int w = (blockIdx.x - 448) >> 4; bx = (blockIdx.x - 448) & 15; nb = 16;
        src = w == 0 ? w0 : w == 1 ? w1 : w == 2 ? w2 : w3;
        n4 = Dd * Dd / 4; slot = 1 + w;
    }
    float m = 0.f;
    for (int i = bx * blockDim.x + threadIdx.x; i < n4; i += nb * blockDim.x) {
        float4 v = src[i];
        m = fmaxf(m, fmaxf(fmaxf(fabsf(v.x), fabsf(v.y)), fmaxf(fabsf(v.z), fabsf(v.w))));
    }
    #pragma unroll
    for (int off = 32; off > 0; off >>= 1) m = fmaxf(m, __shfl_down(m, off, 64));
    __shared__ float sm[4];
    int lane = threadIdx.x & 63, wid = threadIdx.x >> 6;
    if (lane == 0) sm[wid] = m;
    __syncthreads();
    if (threadIdx.x == 0) {
        float mm = fmaxf(fmaxf(sm[0], sm[1]), fmaxf(sm[2], sm[3]));
        atomicMax(slots + slot, __float_as_uint(mm));  // f32 bits compare as uint for >=0
    }
}

// ---------------- fused quant: hidden -> hq8, 4 weights -> Wall8 (1MB apart) ------------
__global__ void quant_all(const float* __restrict__ hidden,
                          const float* __restrict__ w0, const float* __restrict__ w1,
                          const float* __restrict__ w2, const float* __restrict__ w3,
                          const float* __restrict__ amax,
                          char* __restrict__ hq8, char* __restrict__ Wall8) {
    const float* x; char* y; int n4, slot, bx, nb;
    if (blockIdx.x < 1024) { x = hidden; y = hq8; n4 = Mm * Dd / 4; slot = 0; bx = blockIdx.x; nb = 1024; }
    else {
        int w = (blockIdx.x - 1024) >> 5; bx = (blockIdx.x - 1024) & 31; nb = 32;
        x = w == 0 ? w0 : w == 1 ? w1 : w == 2 ? w2 : w3;
        y = Wall8 + ((size_t)w << 20);
        n4 = Dd * Dd / 4; slot = 1 + w;
    }
    float s = qscale(amax[slot]);
    const float4* x4 = (const float4*)x;
    char4* y4 = (char4*)y;
    for (int i = bx * blockDim.x + threadIdx.x; i < n4; i += nb * blockDim.x) {
        float4 v = x4[i];
        char4 q;
        q.x = (char)(int)rintf(v.x / s);
        q.y = (char)(int)rintf(v.y / s);
        q.z = (char)(int)rintf(v.z / s);
        q.w = (char)(int)rintf(v.w / s);
        y4[i] = q;
    }
}

// quant attn output: bf16 in -> int8 out (scale from amax slot; amax was computed on
// the SAME bf16-rounded values, so |v|/s <= 127 exactly -- no overflow clamp needed)
__global__ void quant_a(const unsigned short* __restrict__ x, char* __restrict__ y,
                        const float* __restrict__ amax, int n8) {
    float s = qscale(amax[0]);
    int stride = gridDim.x * blockDim.x;
    const int4* x8 = (const int4*)x;   // 8 bf16 per int4
    int2* y8 = (int2*)y;               // 8 int8
    for (int i = blockIdx.x * blockDim.x + threadIdx.x; i < n8; i += stride) {
        int4 v = x8[i];
        const unsigned short* u = (const unsigned short*)&v;
        char q[8];
        #pragma unroll
        for (int j = 0; j < 8; j++) {
            float f = (float)__builtin_bit_cast(__bf16, u[j]);
            q[j] = (char)(int)rintf(f / s);
        }
        y8[i] = *(const int2*)q;
    }
}

// ---------------- int8 MFMA GEMM core: 128x128 tile, BK=64, 4 waves of 64x64 ------------
// T3 single-barrier double-buffered staging: stage(s+1 -> buf^1) || compute(buf);
// one __syncthreads per K-step (its implicit vmcnt(0) drain is covered by the MFMA phase).
#define GLOAD_LDS16(g, l) __builtin_amdgcn_global_load_lds( \
    (const __attribute__((address_space(1))) unsigned int*)(g), \
    (__attribute__((address_space(3))) unsigned int*)(l), 16, 0, 0)

__device__ __forceinline__ void gemm128_core(const char* __restrict__ A, const char* __restrict__ Bw,
                                             int bm, int bn, int K, int t,
                                             char* At, char* Bt, v4i acc[4][4]) {
    const int lane = t & 63, w = t >> 6;
    const int wm = (w >> 1) * 64, wn = (w & 1) * 64;
    const int lr = lane & 15, kq = lane >> 4;
    const int rs = w * 16 + (lane >> 2);  // wave-contiguous staged row
    const int cc = lane & 3;
    const int NT = K / 64;

    auto stage = [&](int s, int buf) {
        int k0 = s * 64;
        char* Ab = At + buf * 16384;
        char* Bb = Bt + buf * 16384;
        #pragma unroll
        for (int h = 0; h < 2; h++) {
            int r = rs + h * 64;
            int cs = cc ^ ((r >> 1) & 3);  // source-side XOR swizzle
            GLOAD_LDS16(A  + (size_t)(bm + r) * K + k0 + cs * 16, Ab + r * 64 + cc * 16);
            GLOAD_LDS16(Bw + (size_t)(bn + r) * K + k0 + cs * 16, Bb + r * 64 + cc * 16);
        }
    };

    stage(0, 0);
    __syncthreads();
    for (int s = 0; s < NT; s++) {
        const int cur = s & 1;
        if (s + 1 < NT) stage(s + 1, cur ^ 1);

        const char* Ac = At + cur * 16384;
        const char* Bc = Bt + cur * 16384;
        v4i af[4], bf[4];
        #pragma unroll
        for (int mt = 0; mt < 4; mt++) {
            int row = wm + mt * 16 + lr;
            af[mt] = *(const v4i*)(Ac + row * 64 + ((kq ^ ((row >> 1) & 3)) << 4));
        }
        #pragma unroll
        for (int nt = 0; nt < 4; nt++) {
            int row = wn + nt * 16 + lr;
            bf[nt] = *(const v4i*)(Bc + row * 64 + ((kq ^ ((row >> 1) & 3)) << 4));
        }
        #pragma unroll
        for (int mt = 0; mt < 4; mt++)
            #pragma unroll
            for (int nt = 0; nt < 4; nt++)
                acc[mt][nt] = __builtin_amdgcn_mfma_i32_16x16x64_i8(af[mt], bf[nt], acc[mt][nt], 0, 0, 0);

        if (s + 1 < NT) __syncthreads();  // buf[cur^1] ready; buf[cur] free for s+2
    }
}

// Fused Q/K/V projection with LDS-transpose epilogue (coalesced 16B stores, no write
// amplification). Q: bf16 (pre-scaled by 0.125/ln2); K: bf16; V: bf16 transposed [B,H,64,S].
__global__ __launch_bounds__(256) void gemm_qkv(const char* __restrict__ A,
                                                const char* __restrict__ Wall8,
                                                const float* __restrict__ bq,
                                                const float* __restrict__ bk,
                                                const float* __restrict__ bv,
                                                const float* __restrict__ amax,
                                                unsigned short* __restrict__ qb16,
                                                unsigned short* __restrict__ kb16,
                                                unsigned short* __restrict__ vt16) {
    // k-loop: dbuf At|Bt (2x16KB = 32KB); epilogue: 128x136 ushort (34816B)
    __shared__ alignas(16) char pool[34816];
    char* At = pool;
    char* Bt = pool + 8192;
    unsigned short (*Tt)[136] = (unsigned short(*)[136])pool;

    const int t = threadIdx.x, lane = t & 63, w = t >> 6;
    const int mat = blockIdx.x >> 3;
    const int bn = (blockIdx.x & 7) * 128, bm = blockIdx.y * 128;
    const int wm = (w >> 1) * 64, wn = (w & 1) * 64;
    const int lr = lane & 15, kq = lane >> 4;

    const v4i vzero = {0, 0, 0, 0};
    v4i acc[4][4];
    #pragma unroll
    for (int mt = 0; mt < 4; mt++)
        #pragma unroll
        for (int nt = 0; nt < 4; nt++) acc[mt][nt] = vzero;

    const char* Bw = Wall8 + ((size_t)mat << 20);
    gemm128_core(A, Bw, bm, bn, Dd, t, At, Bt, acc);

    const float* bias = mat == 0 ? bq : mat == 1 ? bk : bv;
    float sc = qscale(amax[0]) * qscale(amax[1 + mat]);
    float pm = (mat == 0) ? QPOSTMUL : 1.0f;

    __syncthreads();  // all waves done reading staging before Tt overwrites the pool

    // ---- phase A: acc -> bf16 -> LDS tile ----
    if (mat != 2) {
        // Tt[m][n] (row-major target)
        #pragma unroll
        for (int nt = 0; nt < 4; nt++) {
            int n_l = wn + nt * 16 + lr;
            float bv_ = bias[bn + n_l];
            #pragma unroll
            for (int mt = 0; mt < 4; mt++) {
                int m_l = wm + mt * 16 + kq * 4;
                #pragma unroll
                for (int rg = 0; rg < 4; rg++)
                    Tt[m_l + rg][n_l] = bf16rtn(((float)acc[mt][nt][rg] * sc + bv_) * pm);
            }
        }
    } else {
        // Tt[n][m] (V^T target): lane's 4 consecutive m -> one 8B write
        #pragma unroll
        for (int nt = 0; nt < 4; nt++) {
            int n_l = wn + nt * 16 + lr;
            float bv_ = bias[bn + n_l];
            #pragma unroll
            for (int mt = 0; mt < 4; mt++) {
                int m_l = wm + mt * 16 + kq * 4;
                ushort4 hv;
                hv.x = bf16rtn((float)acc[mt][nt][0] * sc + bv_);
                hv.y = bf16rtn((float)acc[mt][nt][1] * sc + bv_);
                hv.z = bf16rtn((float)acc[mt][nt][2] * sc + bv_);
                hv.w = bf16rtn((float)acc[mt][nt][3] * sc + bv_);
                *(ushort4*)&Tt[n_l][m_l] = hv;
            }
        }
    }
    __syncthreads();

    // ---- phase B: coalesced 16B stores of contiguous 256B rows ----
    {
        int row = t >> 1, half = t & 1;
        unsigned short* dst;
        if (mat != 2) {
            dst = (mat == 0 ? qb16 : kb16) + (size_t)(bm + row) * Dd + bn + half * 64;
        } else {
            int n = bn + row;
            int e = n & 63, hc = n >> 6;
            int b_ = bm >> 11, s_ = (bm & 2047) + half * 64;
            dst = vt16 + (((size_t)(b_ * Hh + hc) * 64 + e) * Ss) + s_;
        }
        const unsigned short* srcl = &Tt[row][half * 64];
        #pragma unroll
        for (int c = 0; c < 8; c++)
            *(int4*)(dst + c * 8) = *(const int4*)(srcl + c * 8);
    }
}

// O-projection: 128m x 64n tile, dbuf single-barrier k-loop. f32 output.
__global__ __launch_bounds__(256) void gemm_o(const char* __restrict__ A,
                                              const char* __restrict__ Bw,
                                              const float* __restrict__ bias,
                                              const float* __restrict__ amaxA,
                                              const float* __restrict__ amaxB,
                                              float* __restrict__ C) {
    // dbuf: A0@0(8K), B0@8K(4K), A1@12K, B1@20K -> 24576B
    __shared__ alignas(16) char pool[24576];
    const int t = threadIdx.x, lane = t & 63, w = t >> 6;
    const int bn = blockIdx.x * 64, bm = blockIdx.y * 128;
    const int wm = (w >> 1) * 64, wn = (w & 1) * 32;
    const int lr = lane & 15, kq = lane >> 4;
    const int rs = t >> 2, cc = t & 3;
    const int cs = cc ^ ((rs >> 1) & 3);
    const int rs2 = rs + 64, cs2 = cc ^ ((rs2 >> 1) & 3);

    auto stage = [&](int s, int buf) {
        int k0 = s * 64;
        char* Ab = pool + buf * 12288;
        char* Bb = Ab + 8192;
        GLOAD_LDS16(A  + (size_t)(bm + rs)  * Dd + k0 + cs  * 16, Ab + rs  * 64 + cc * 16);
        GLOAD_LDS16(A  + (size_t)(bm + rs2) * Dd + k0 + cs2 * 16, Ab + rs2 * 64 + cc * 16);
        GLOAD_LDS16(Bw + (size_t)(bn + rs)  * Dd + k0 + cs  * 16, Bb + rs  * 64 + cc * 16);
    };

    const v4i vzero = {0, 0, 0, 0};
    v4i acc[4][2];
    #pragma unroll
    for (int mt = 0; mt < 4; mt++) { acc[mt][0] = vzero; acc[mt][1] = vzero; }

    stage(0, 0);
    __syncthreads();
    const int NT = Dd / 64;
    for (int s = 0; s < NT; s++) {
        const int cur = s & 1;
        if (s + 1 < NT) stage(s + 1, cur ^ 1);

        const char* Ac = pool + cur * 12288;
        const char* Bc = Ac + 8192;
        v4i af[4], bf[2];
        #pragma unroll
        for (int mt = 0; mt < 4; mt++) {
            int row = wm + mt * 16 + lr;
            af[mt] = *(const v4i*)(Ac + row * 64 + ((kq ^ ((row >> 1) & 3)) << 4));
        }
        #pragma unroll
        for (int nt = 0; nt < 2; nt++) {
            int row = wn + nt * 16 + lr;
            bf[nt] = *(const v4i*)(Bc + row * 64 + ((kq ^ ((row >> 1) & 3)) << 4));
        }
        #pragma unroll
        for (int mt = 0; mt < 4; mt++)
            #pragma unroll
            for (int nt = 0; nt < 2; nt++)
                acc[mt][nt] = __builtin_amdgcn_mfma_i32_16x16x64_i8(af[mt], bf[nt], acc[mt][nt], 0, 0, 0);

        if (s + 1 < NT) __syncthreads();
    }

    float sc = qscale(amaxA[0]) * qscale(amaxB[0]);
    #pragma unroll
    for (int nt = 0; nt < 2; nt++) {
        int n = bn + wn + nt * 16 + lr;
        float bv_ = bias[n];
        #pragma unroll
        for (int mt = 0; mt < 4; mt++)
            #pragma unroll
            for (int rg = 0; rg < 4; rg++) {
                int m = bm + wm + mt * 16 + kq * 4 + rg;
                C[(size_t)m * Dd + n] = (float)acc[mt][nt][rg] * sc + bv_;
            }
    }
}

// ---------------- MFMA flash attention — swapped-QK + XCD-aware block swizzle ----------
// R3 structure (56.1 µs) + T1: the 16 q-tile blocks sharing one (b,h)'s K/V (512 KB)
// are remapped so each XCD owns 4 COMPLETE (b,h) groups (2 MB < 4 MB XCD-L2) instead
// of receiving slices of all 32 -> K/V streams become L2-resident after first touch.
// Output ab is bf16 (half write traffic); fused amax computed on post-rounding values
// so quant_a's |v|/s <= 127 exactly.
__global__ __launch_bounds__(512, 4) void attn_mfma(
    const unsigned short* __restrict__ qb16, const unsigned short* __restrict__ kb16,
    const unsigned short* __restrict__ vt16,
    const float* __restrict__ mask, unsigned short* __restrict__ Ob,
    unsigned* __restrict__ amax_out) {
    // K/V staging for both groups (36864B); overlaid by Osh[128][65]+Lsh2 in epilogue
    __shared__ alignas(16) char apool[36864];
    unsigned short (*Ks)[64][72] = (unsigned short(*)[64][72])apool;             // [2][64][72]
    unsigned short (*Vs)[64][72] = (unsigned short(*)[64][72])(apool + 18432);   // [2][64][72]
    __shared__ float wred[4];

    const int t = threadIdx.x, lane = t & 63, wq = t >> 6;
    const int g = wq >> 2, wq4 = wq & 3, tg = t & 255;
    const int ln31 = lane & 31, h5 = lane >> 5;

    // T1 XCD swizzle: linear id L -> xcd = L%8 (HW round-robin); give each XCD
    // 4 complete (b,h) groups x 16 q-tiles.
    const int L = blockIdx.x + (blockIdx.y << 4) + (blockIdx.z << 8);
    const int xcd = L & 7, rest = L >> 3;
    const int qi = rest & 15, gq = rest >> 4;       // q-tile, group-slot on this XCD
    const int gbh = gq * 8 + xcd;                   // (b,h) group in [0,32)
    const int h = gbh & 15, b = gbh >> 4;
    const int q0 = qi * 128;
    const int kbase = g << 10;

    // Q fragments (B operand after swap): q-col = ln31, k = c*16 + h5*8 + j
    bf16x8 qf[4];
    {
        int qrow = q0 + wq4 * 32 + ln31;
        const unsigned short* qb_ = qb16 + ((size_t)(b * Ss + qrow)) * Dd + h * 64 + h5 * 8;
        #pragma unroll
        for (int c = 0; c < 4; c++) qf[c] = *(const bf16x8*)(qb_ + c * 16);
    }

    const int srow = tg >> 2, cp = (tg & 3) * 2;
    const int rho = (srow >> 1) + (srow & 1) * 32;  // interleave permute for K
    int4 pk0, pk1, pv0, pv1; float pmv = 1.f;
    auto prefetch = [&](int k0) {
        const unsigned short* gk = kb16 + ((size_t)(b * Ss + k0 + srow)) * Dd + h * 64 + cp * 8;
        const unsigned short* gv = vt16 + (((size_t)(b * Hh + h) * 64 + srow)) * Ss + k0 + cp * 8;
        pk0 = *(const int4*)gk; pk1 = *(const int4*)(gk + 8);
        pv0 = *(const int4*)gv; pv1 = *(const int4*)(gv + 8);
        pmv = mask[b * Ss + k0 + lane];  // per-wave copy of the tile's 64 mask values
    };

    f32x16 o0 = 0.f, o1 = 0.f;
    float la0 = 0.f, la1 = 0.f, la2 = 0.f, la3 = 0.f;

    prefetch(kbase);
    for (int k0 = kbase; k0 < kbase + Ss / 2; k0 += 64) {
        __syncthreads();
        *(int4*)&Ks[g][rho][cp * 8]      = pk0;
        *(int4*)&Ks[g][rho][cp * 8 + 8]  = pk1;
        *(int4*)&Vs[g][srow][cp * 8]     = pv0;
        *(int4*)&Vs[g][srow][cp * 8 + 8] = pv1;
        unsigned long long bm = __ballot(pmv > 0.5f);
        __syncthreads();
        if (k0 + 64 < kbase + Ss / 2) prefetch(k0 + 64);  // in flight during MFMA phase

        // QK^T SWAPPED: sc = mfma(K, Q). D row = key-in-tile, col = q (ln31).
        // tile0 = even orig keys (staged rows 0-31), tile1 = odd (rows 32-63).
        f32x16 sc0 = 0.f, sc1 = 0.f;
        __builtin_amdgcn_s_setprio(1);
        #pragma unroll
        for (int c = 0; c < 4; c++) {
            bf16x8 kh0 = *(const bf16x8*)&Ks[g][ln31][c * 16 + h5 * 8];
            bf16x8 kh1 = *(const bf16x8*)&Ks[g][32 + ln31][c * 16 + h5 * 8];
            sc0 = __builtin_amdgcn_mfma_f32_32x32x16_bf16(kh0, qf[c], sc0, 0, 0, 0);
            sc1 = __builtin_amdgcn_mfma_f32_32x32x16_bf16(kh1, qf[c], sc1, 0, 0, 0);
        }
        __builtin_amdgcn_s_setprio(0);

        // Fused softmax + PV per d-chunk c: reg r=4c+j holds keys 16c+8*h5+2j (sc0)
        // and +1 (sc1); PV chunk c consumes exactly those 8 -> in-register A-fragment.
        #pragma unroll
        for (int c = 0; c < 4; c++) {
            float e0[4], e1[4];
            #pragma unroll
            for (int j = 0; j < 4; j++) {
                e0[j] = __builtin_amdgcn_exp2f(sc0[4 * c + j]);
                e1[j] = __builtin_amdgcn_exp2f(sc1[4 * c + j]);
            }
            if (bm != ~0ull) {
                #pragma unroll
                for (int j = 0; j < 4; j++) {
                    int kk = 16 * c + 8 * h5 + 2 * j;
                    e0[j] *= (float)(int)((bm >> kk) & 1);
                    e1[j] *= (float)(int)((bm >> (kk + 1)) & 1);
                }
            }
            la0 += e0[0] + e1[0];
            la1 += e0[1] + e1[1];
            la2 += e0[2] + e1[2];
            la3 += e0[3] + e1[3];

            uint4 pw;
            pw.x = pack_bf16x2(e0[0], e1[0]);
            pw.y = pack_bf16x2(e0[1], e1[1]);
            pw.z = pack_bf16x2(e0[2], e1[2]);
            pw.w = pack_bf16x2(e0[3], e1[3]);
            bf16x8 pf = __builtin_bit_cast(bf16x8, pw);
            bf16x8 vh0 = *(const bf16x8*)&Vs[g][ln31][c * 16 + h5 * 8];
            bf16x8 vh1 = *(const bf16x8*)&Vs[g][32 + ln31][c * 16 + h5 * 8];
            __builtin_amdgcn_s_setprio(1);
            o0 = __builtin_amdgcn_mfma_f32_32x32x16_bf16(pf, vh0, o0, 0, 0, 0);
            o1 = __builtin_amdgcn_mfma_f32_32x32x16_bf16(pf, vh1, o1, 0, 0, 0);
            __builtin_amdgcn_s_setprio(0);
        }
    }

    // ---- combine epilogue: O = (O_g0 + O_g1) / (l_g0 + l_g1) ----
    // lane's l covers its h5-half's 32 keys/tile; pair-sum across halves (same q).
    float lsum = (la0 + la1) + (la2 + la3);
    lsum += __shfl_xor(lsum, 32, 64);

    __syncthreads();  // all K/V staging reads done; safe to overlay on apool
    float (*Osh)[65] = (float(*)[65])apool;               // 128*65*4 = 33280B
    float (*Lsh2)[128] = (float(*)[128])(apool + 33280);  // [2][128] f32, 1024B

    if (lane < 32) Lsh2[g][wq4 * 32 + ln31] = lsum;  // per-q-row l partial for this group
    if (g == 1) {
        #pragma unroll
        for (int r = 0; r < 16; r++) {
            int rl = wq4 * 32 + (r & 3) + 8 * (r >> 2) + 4 * h5;
            Osh[rl][ln31]      = o0[r];
            Osh[rl][32 + ln31] = o1[r];
        }
    }
    __syncthreads();
    if (g == 0) {
        float lmax = 0.f;
        #pragma unroll
        for (int r = 0; r < 16; r++) {
            int rl = wq4 * 32 + (r & 3) + 8 * (r >> 2) + 4 * h5;
            float inv = 1.0f / (Lsh2[0][rl] + Lsh2[1][rl]);
            size_t ro = ((size_t)(b * Ss + q0 + rl)) * Dd + h * 64;
            // round to bf16 FIRST; amax on rounded values (quant safety: |v|/s <= 127)
            __bf16 b0 = (__bf16)((o0[r] + Osh[rl][ln31]) * inv);
            __bf16 b1 = (__bf16)((o1[r] + Osh[rl][32 + ln31]) * inv);
            Ob[ro + ln31]      = __builtin_bit_cast(unsigned short, b0);
            Ob[ro + 32 + ln31] = __builtin_bit_cast(unsigned short, b1);
            lmax = fmaxf(lmax, fmaxf(fabsf((float)b0), fabsf((float)b1)));
        }
        #pragma unroll
        for (int off = 32; off > 0; off >>= 1) lmax = fmaxf(lmax, __shfl_xor(lmax, off, 64));
        if (lane == 0) wred[wq4] = lmax;
    }
    __syncthreads();
    if (t == 0) {
        float m = fmaxf(fmaxf(wred[0], wred[1]), fmaxf(wred[2], wred[3]));
        atomicMax(amax_out, __float_as_uint(m));
    }
}

// ---------------- launch ----------------
extern "C" void kernel_launch(void* const* d_in, const int* in_sizes, int n_in,
                              void* d_out, int out_size, void* d_ws, size_t ws_size,
                              hipStream_t stream) {
    const float* hidden = (const float*)d_in[0];
    const float* mask   = (const float*)d_in[1];
    const float* Wq = (const float*)d_in[2];
    const float* bq = (const float*)d_in[3];
    const float* Wk = (const float*)d_in[4];
    const float* bk = (const float*)d_in[5];
    const float* Wv = (const float*)d_in[6];
    const float* bv = (const float*)d_in[7];
    const float* Wo = (const float*)d_in[8];
    const float* bo = (const float*)d_in[9];
    float* out = (float*)d_out;

    char* ws = (char*)d_ws;
    float* scal = (float*)ws;  // amax slots 0..5
    size_t off = 1024;
    const size_t szH8 = (size_t)Mm * Dd;                           // 4 MB
    const size_t szHb = (size_t)Mm * Dd * sizeof(unsigned short);  // 8.39 MB
    char* hq8   = ws + off; off += szH8;
    char* Wall8 = ws + off; off += 4u << 20;  // Wq|Wk|Wv|Wo, 1MB each
    char* aq8   = ws + off; off += szH8;
    unsigned short* qb16 = (unsigned short*)(ws + off); off += szHb;
    unsigned short* kb16 = (unsigned short*)(ws + off); off += szHb;
    unsigned short* vt16 = (unsigned short*)(ws + off); off += szHb;
    unsigned short* ab   = (unsigned short*)(ws + off); off += szHb;  // bf16 attn out

    hipMemsetAsync(scal, 0, 64, stream);

    amax_all<<<512, 256, 0, stream>>>((const float4*)hidden, (const float4*)Wq,
                                      (const float4*)Wk, (const float4*)Wv, (const float4*)Wo,
                                      (unsigned*)scal);
    quant_all<<<1152, 256, 0, stream>>>(hidden, Wq, Wk, Wv, Wo, scal, hq8, Wall8);

    gemm_qkv<<<dim3(24, 32), 256, 0, stream>>>(hq8, Wall8, bq, bk, bv, scal,
                                               qb16, kb16, vt16);

    attn_mfma<<<dim3(Ss / 128, Hh, Bb), 512, 0, stream>>>(qb16, kb16, vt16,
                                                          mask, ab, (unsigned*)(scal + 5));

    quant_a<<<1024, 256, 0, stream>>>(ab, aq8, scal + 5, Mm * Dd / 8);

    gemm_o<<<dim3(16, 32), 256, 0, stream>>>(aq8, Wall8 + (3u << 20), bo,
                                             scal + 5, scal + 4, out);
}